// Round 8
// baseline (562.767 us; speedup 1.0000x reference)
//
#include <hip/hip_runtime.h>
#include <hip/hip_bf16.h>
#include <math.h>

// B=1, S=2048, D=2048, H=32, KV=8, HD=64, G=4.
#define S_LEN 2048
#define D_MODEL 2048
#define N_H 32
#define N_KV 8
#define HD 64

typedef __attribute__((ext_vector_type(8))) short short8;   // 8 bf16 (A/B frag)
typedef __attribute__((ext_vector_type(4))) float floatx4;  // C/D frag
typedef unsigned short u16;
typedef unsigned int u32;

#define QSCALE 0.18033688011112042f   // (1/8) * log2(e): folded into Q -> exp2 domain

#if defined(__has_builtin)
#if __has_builtin(__builtin_amdgcn_exp2f)
#define EXP2(x) __builtin_amdgcn_exp2f(x)
#else
#define EXP2(x) __expf(0.6931471805599453f * (x))
#endif
#else
#define EXP2(x) __expf(0.6931471805599453f * (x))
#endif

// round-to-nearest-even fp32 -> bf16
__device__ __forceinline__ u16 f2bf(float f) {
    union { float f; u32 u; } v; v.f = f;
    u32 r = v.u + 0x7fffu + ((v.u >> 16) & 1u);
    return (u16)(r >> 16);
}

// async global->LDS, 16B/lane. LDS dest = wave-uniform base + lane*16.
__device__ __forceinline__ void gload16(const void* gp, void* lp) {
    __builtin_amdgcn_global_load_lds(
        (const __attribute__((address_space(1))) unsigned int*)gp,
        (__attribute__((address_space(3))) unsigned int*)lp,
        16, 0, 0);
}

// Device-scope grid barrier (persistent-kernel pattern, guide G16):
// release fence -> arrive -> spin (agent-scope load) -> acquire fence.
// Safe because all NBLK blocks are co-resident by construction.
__device__ __forceinline__ void gbar(u32* cnt, u32 target) {
    __syncthreads();
    if (threadIdx.x == 0) {
        __threadfence();                       // release prior global writes
        atomicAdd(cnt, 1u);
        while (__hip_atomic_load(cnt, __ATOMIC_RELAXED,
                                 __HIP_MEMORY_SCOPE_AGENT) < target)
            __builtin_amdgcn_s_sleep(2);
        __threadfence();                       // acquire other blocks' writes
    }
    __syncthreads();
}

#define NBLK 768

// ---------------------------------------------------------------------------
// ROUND-14: single persistent kernel. Rationale: every per-kernel structure
// is at/above its shape-reference plateau (qkv 549 TF > m97@2048's 320 TF;
// r1-r6 perturbations all ±10%), while kernel-sum (~140-150us) vs e2e
// (208us) shows ~55-70us of inter-kernel cost (dispatch ramps + kernel-
// boundary cache flush + graph gaps) stable across 8 runs. Fusing the 4
// phases into one 768-block persistent kernel with device-scope spin
// barriers removes 3 kernel boundaries. Phase bodies are VERBATIM copies of
// the round-13 proven kernels; only LDS aliasing (40KB union) and block-id
// mapping changed. Co-residency guaranteed: LDS 40KB -> 3 blocks/CU
// (123KB < 160KB), launch_bounds(256,3), grid 768 = 3 x 256CU exactly.
// attn's 1024 variable-cost items go through an atomic work queue
// (heavy-first pop = dynamic balance over 768 workers).
// ---------------------------------------------------------------------------
__global__ __launch_bounds__(256, 3) void fused_all(
    const float* __restrict__ x,  const float* __restrict__ Wq,
    const float* __restrict__ Wk, const float* __restrict__ Wv,
    const float* __restrict__ Wo, const float* __restrict__ inv_freq,
    u16* __restrict__ xb,  u16* __restrict__ wqkv, u16* __restrict__ wob,
    u16* __restrict__ qhb, u16* __restrict__ khb,  u16* __restrict__ vtb,
    u16* __restrict__ aob, float2* __restrict__ tab,
    float* __restrict__ out, u32* __restrict__ bar, u32* __restrict__ queue)
{
    __shared__ u16 LDS[20480];           // 40 KB union for all phases
    __shared__ int qslot;
    const int tid = threadIdx.x;
    const int bid = blockIdx.x;

    // ================= phase 0: cast all inputs + RoPE table =================
    {
        for (int c = bid * 256 + tid; c < 3670016; c += NBLK * 256) {
            const int i = c * 4;
            const int row = i >> 11;
            const int col = i & 2047;
            const float* src;
            u16* dst;
            if (row < 2048)      { src = x  + (size_t)row * 2048 + col;          dst = xb + i; }
            else if (row < 4096) { src = Wq + (size_t)(row - 2048) * 2048 + col; dst = wqkv + (i - 2048 * 2048); }
            else if (row < 4608) { src = Wk + (size_t)(row - 4096) * 2048 + col; dst = wqkv + (i - 2048 * 2048); }
            else if (row < 5120) { src = Wv + (size_t)(row - 4608) * 2048 + col; dst = wqkv + (i - 2048 * 2048); }
            else                 { src = Wo + (size_t)(row - 5120) * 2048 + col; dst = wob + (i - 5120 * 2048); }
            const float4 v = *(const float4*)src;
            ushort4 o;
            o.x = f2bf(v.x); o.y = f2bf(v.y); o.z = f2bf(v.z); o.w = f2bf(v.w);
            *(ushort4*)dst = o;
        }
        const int t0 = bid * 256 + tid;
        if (t0 < 65536) {                 // s = t0>>5, d = t0&31
            float sn, cs;
            sincosf((float)(t0 >> 5) * inv_freq[t0 & 31], &sn, &cs);
            tab[t0] = make_float2(cs, sn);
        }
    }
    gbar(bar, NBLK);

    // ================= phase 1: QKV GEMM + RoPE/pack epilogue ================
    // LDS alias: As[cur][x] = LDS[cur*2048+x]; Bs[cur][x] = LDS[4096+cur*4096+x]
    {
        const int w    = tid >> 6;
        const int lane = tid & 63;
        const int lr   = lane & 15;
        const int quad = lane >> 4;
        const int bm = (bid & 31) * 64, bn = (bid >> 5) * 128;
        const int wm = (w & 1) * 32, wn = (w >> 1) * 64;
        const int srow = tid >> 2;
        const int sch  = (tid & 3) * 8;
        const u16* Ag = xb   + (size_t)(bm + srow) * 2048 + sch;
        const u16* Bg = wqkv + (size_t)(bn + srow) * 2048 + sch;
        const int loff = srow * 32 + sch;
        const size_t gstride = (size_t)64 * 2048;

        floatx4 acc[2][4];
#pragma unroll
        for (int i = 0; i < 2; ++i)
#pragma unroll
            for (int j = 0; j < 4; ++j) acc[i][j] = floatx4{0.f, 0.f, 0.f, 0.f};

        gload16(Ag, &LDS[loff]);
        gload16(Bg, &LDS[4096 + loff]);
        gload16(Bg + gstride, &LDS[4096 + loff + 2048]);
        __syncthreads();

        for (int k0 = 0; k0 < 2048; k0 += 32) {
            const int cur = (k0 >> 5) & 1;
            if (k0 + 32 < 2048) {
                const int nb = cur ^ 1;
                gload16(Ag + k0 + 32, &LDS[nb * 2048 + loff]);
                gload16(Bg + k0 + 32, &LDS[4096 + nb * 4096 + loff]);
                gload16(Bg + gstride + k0 + 32, &LDS[4096 + nb * 4096 + loff + 2048]);
            }
            short8 af[2], bf[4];
#pragma unroll
            for (int t = 0; t < 2; ++t)
                af[t] = *(const short8*)&LDS[cur * 2048 + (wm + t * 16 + lr) * 32 + quad * 8];
#pragma unroll
            for (int t = 0; t < 4; ++t)
                bf[t] = *(const short8*)&LDS[4096 + cur * 4096 + (wn + t * 16 + lr) * 32 + quad * 8];
#pragma unroll
            for (int im = 0; im < 2; ++im)
#pragma unroll
                for (int in = 0; in < 4; ++in)
                    acc[im][in] = __builtin_amdgcn_mfma_f32_16x16x32_bf16(
                        af[im], bf[in], acc[im][in], 0, 0, 0);
            __syncthreads();
        }

        const int c0 = bn + wn;
        if (bn < 2048) {                           // ---- Q: rope + scale ----
            const int h = c0 >> 6;
#pragma unroll
            for (int p = 0; p < 2; ++p) {
                const int d = p * 16 + lr;
#pragma unroll
                for (int im = 0; im < 2; ++im)
#pragma unroll
                    for (int r = 0; r < 4; ++r) {
                        const int s = bm + wm + im * 16 + quad * 4 + r;
                        const float2 t = tab[s * 32 + d];
                        const float cs = t.x, sn = t.y;
                        const float xl = acc[im][p][r], xh = acc[im][p + 2][r];
                        u16* qrow = qhb + ((size_t)h * S_LEN + s) * HD;
                        qrow[d]      = f2bf((xl * cs - xh * sn) * QSCALE);
                        qrow[d + 32] = f2bf((xh * cs + xl * sn) * QSCALE);
                    }
            }
        } else if (bn < 2560) {                    // ---- K: rope ----
            const int kv = (c0 - 2048) >> 6;
#pragma unroll
            for (int p = 0; p < 2; ++p) {
                const int d = p * 16 + lr;
#pragma unroll
                for (int im = 0; im < 2; ++im)
#pragma unroll
                    for (int r = 0; r < 4; ++r) {
                        const int s = bm + wm + im * 16 + quad * 4 + r;
                        const float2 t = tab[s * 32 + d];
                        const float cs = t.x, sn = t.y;
                        const float xl = acc[im][p][r], xh = acc[im][p + 2][r];
                        u16* krow = khb + ((size_t)kv * S_LEN + s) * HD;
                        krow[d]      = f2bf(xl * cs - xh * sn);
                        krow[d + 32] = f2bf(xh * cs + xl * sn);
                    }
            }
        } else {                                   // ---- V: transpose pack ----
            const int kv = (c0 - 2560) >> 6;
#pragma unroll
            for (int im = 0; im < 2; ++im)
#pragma unroll
                for (int in = 0; in < 4; ++in) {
                    const int dfull = in * 16 + lr;
                    const int s0 = bm + wm + im * 16 + quad * 4;
                    ushort4 o;
                    o.x = f2bf(acc[im][in][0]); o.y = f2bf(acc[im][in][1]);
                    o.z = f2bf(acc[im][in][2]); o.w = f2bf(acc[im][in][3]);
                    *(ushort4*)&vtb[((size_t)kv * HD + dfull) * S_LEN + s0] = o;
                }
        }
    }
    gbar(bar, 2 * NBLK);

    // ================= phase 2: flash attention (work queue) =================
    // LDS alias: QPs[x]=LDS[x]; Ks[b][x]=LDS[4096+b*4096+x]; Vs[b][x]=LDS[12288+b*4096+x]
    {
        const int w    = tid >> 6;
        const int lr   = tid & 15;
        const int quad = (tid >> 4) & 3;
        const int grow = tid >> 3;
        const int gp   = tid & 7;
        const int q1   = quad >> 1;
        const int lr7  = lr & 7;
        const int pwbase = (w * 16 + lr) * 64 + (quad & 1) * 4;

        for (;;) {
            if (tid == 0) qslot = (int)atomicAdd(queue, 1u);
            __syncthreads();
            const int item = qslot;
            if (item >= 1024) break;

            const int h  = item & 31;
            const int qb = 31 - (item >> 5);     // heavy q-tiles popped first
            const int kv = h >> 2;
            const u16* Qg = qhb + ((size_t)h * S_LEN + (size_t)qb * 64) * HD;
            const u16* Kg = khb + (size_t)kv * S_LEN * HD;
            const u16* Vg = vtb + (size_t)kv * HD * S_LEN;

#pragma unroll
            for (int j = 0; j < 2; ++j) {
                const int r = j * 32 + grow;
                gload16(Qg + (size_t)r * HD + ((gp ^ (r & 7)) * 8), &LDS[r * 64 + gp * 8]);
                gload16(Kg + (size_t)r * HD + ((gp ^ (r & 7)) * 8), &LDS[4096 + r * 64 + gp * 8]);
                gload16(Vg + (size_t)r * S_LEN + ((gp ^ (r & 7)) * 8), &LDS[12288 + r * 64 + gp * 8]);
            }
            __syncthreads();

            const int wq0 = qb * 64 + w * 16;

            short8 qf[2];
#pragma unroll
            for (int kh = 0; kh < 2; ++kh) {
                const int row = w * 16 + lr;
                const int c   = kh * 4 + quad;
                qf[kh] = *(const short8*)&LDS[row * 64 + ((c ^ (row & 7)) * 8)];
            }

            float l_lane = 0.f;
            floatx4 oacc[4];
#pragma unroll
            for (int dn = 0; dn < 4; ++dn) oacc[dn] = floatx4{0.f, 0.f, 0.f, 0.f};

            for (int kt = 0; kt <= qb; ++kt) {
                const int buf = kt & 1;
                if (kt < qb) {
                    const int nb = buf ^ 1;
#pragma unroll
                    for (int j = 0; j < 2; ++j) {
                        const int r = j * 32 + grow;
                        gload16(Kg + (size_t)((kt + 1) * 64 + r) * HD + ((gp ^ (r & 7)) * 8),
                                &LDS[4096 + nb * 4096 + r * 64 + gp * 8]);
                        gload16(Vg + (size_t)r * S_LEN + (kt + 1) * 64 + ((gp ^ (r & 7)) * 8),
                                &LDS[12288 + nb * 4096 + r * 64 + gp * 8]);
                    }
                }
                if (64 * kt <= wq0 + 15) {
                    floatx4 st[4];
#pragma unroll
                    for (int in = 0; in < 4; ++in) st[in] = floatx4{0.f, 0.f, 0.f, 0.f};
#pragma unroll
                    for (int in = 0; in < 4; ++in)
#pragma unroll
                        for (int kh = 0; kh < 2; ++kh) {
                            const int row = in * 16 + lr;
                            const int c   = kh * 4 + quad;
                            const short8 kf = *(const short8*)
                                &LDS[4096 + buf * 4096 + row * 64 + ((c ^ (row & 7)) * 8)];
                            st[in] = __builtin_amdgcn_mfma_f32_16x16x32_bf16(
                                kf, qf[kh], st[in], 0, 0, 0);
                        }

                    const bool need_mask = (kt * 64 + 63) > wq0;
                    const int qglob = wq0 + lr;
#pragma unroll
                    for (int in = 0; in < 4; ++in)
#pragma unroll
                        for (int r = 0; r < 4; ++r) {
                            float s = st[in][r];
                            if (need_mask) {
                                const int kg = kt * 64 + in * 16 + quad * 4 + r;
                                if (kg > qglob) s = -1e30f;
                            }
                            const float p = EXP2(s);
                            st[in][r] = p;
                            l_lane += p;
                        }

#pragma unroll
                    for (int in = 0; in < 4; ++in) {
                        const int chunk = (((in * 2 + q1) ^ lr7) << 3);
                        float2 lo2; lo2.x = st[in][0]; lo2.y = st[in][1];
                        float2 hi2; hi2.x = st[in][2]; hi2.y = st[in][3];
                        __hip_bfloat162 blo = __float22bfloat162_rn(lo2);
                        __hip_bfloat162 bhi = __float22bfloat162_rn(hi2);
                        *(u32*)&LDS[pwbase + chunk]     = *(u32*)&blo;
                        *(u32*)&LDS[pwbase + chunk + 2] = *(u32*)&bhi;
                    }

#pragma unroll
                    for (int kc = 0; kc < 2; ++kc) {
                        const int prow = w * 16 + lr;
                        const short8 pf = *(const short8*)
                            &LDS[prow * 64 + (((kc * 4 + quad) ^ (prow & 7)) * 8)];
#pragma unroll
                        for (int dn = 0; dn < 4; ++dn) {
                            const int vrow = dn * 16 + lr;
                            const int c    = kc * 4 + quad;
                            const short8 vf = *(const short8*)
                                &LDS[12288 + buf * 4096 + vrow * 64 + ((c ^ (vrow & 7)) * 8)];
                            oacc[dn] = __builtin_amdgcn_mfma_f32_16x16x32_bf16(
                                pf, vf, oacc[dn], 0, 0, 0);
                        }
                    }
                }
                __syncthreads();
            }

            float lv = l_lane;
            lv += __shfl_xor(lv, 16);
            lv += __shfl_xor(lv, 32);
#pragma unroll
            for (int r = 0; r < 4; ++r) {
                const float inv = 1.f / __shfl(lv, quad * 4 + r);
                const size_t row = (size_t)(wq0 + quad * 4 + r);
#pragma unroll
                for (int dn = 0; dn < 4; ++dn)
                    aob[row * D_MODEL + h * 64 + dn * 16 + lr] =
                        f2bf(oacc[dn][r] * inv);
            }
        }
    }
    gbar(bar, 3 * NBLK);

    // ================= phase 3: output projection =================
    // LDS alias: As[cur][x] = LDS[cur*4096+x]; Bs[cur][x] = LDS[8192+cur*4096+x]
    {
        const int w    = tid >> 6;
        const int lane = tid & 63;
        const int lr   = lane & 15;
        const int quad = lane >> 4;
        const int wm = w * 16;
        const int srow = tid >> 3;
        const int sch  = tid & 7;

        for (int it = bid; it < 1024; it += NBLK) {
            const int bm = (it & 31) * 64, bn = (it >> 5) * 64;
            __syncthreads();                      // LDS reuse guard

            floatx4 acc[4];
#pragma unroll
            for (int j = 0; j < 4; ++j) acc[j] = floatx4{0.f, 0.f, 0.f, 0.f};

#pragma unroll
            for (int j = 0; j < 2; ++j) {
                const int r = j * 32 + srow;
                gload16(aob + (size_t)(bm + r) * 2048 + ((sch ^ (r & 7)) * 8),
                        &LDS[r * 64 + sch * 8]);
                gload16(wob + (size_t)(bn + r) * 2048 + ((sch ^ (r & 7)) * 8),
                        &LDS[8192 + r * 64 + sch * 8]);
            }
            __syncthreads();

            for (int k0 = 0; k0 < 2048; k0 += 64) {
                const int cur = (k0 >> 6) & 1;
                if (k0 + 64 < 2048) {
                    const int nb = cur ^ 1;
#pragma unroll
                    for (int j = 0; j < 2; ++j) {
                        const int r = j * 32 + srow;
                        gload16(aob + (size_t)(bm + r) * 2048 + k0 + 64 + ((sch ^ (r & 7)) * 8),
                                &LDS[nb * 4096 + r * 64 + sch * 8]);
                        gload16(wob + (size_t)(bn + r) * 2048 + k0 + 64 + ((sch ^ (r & 7)) * 8),
                                &LDS[8192 + nb * 4096 + r * 64 + sch * 8]);
                    }
                }
#pragma unroll
                for (int kk = 0; kk < 2; ++kk) {
                    short8 af, bf[4];
                    {
                        const int row = wm + lr;
                        const int c   = kk * 4 + quad;
                        af = *(const short8*)&LDS[cur * 4096 + row * 64 + ((c ^ (row & 7)) * 8)];
                    }
#pragma unroll
                    for (int in = 0; in < 4; ++in) {
                        const int row = in * 16 + lr;
                        const int c   = kk * 4 + quad;
                        bf[in] = *(const short8*)&LDS[8192 + cur * 4096 + row * 64 + ((c ^ (row & 7)) * 8)];
                    }
#pragma unroll
                    for (int in = 0; in < 4; ++in)
                        acc[in] = __builtin_amdgcn_mfma_f32_16x16x32_bf16(
                            af, bf[in], acc[in], 0, 0, 0);
                }
                __syncthreads();
            }

#pragma unroll
            for (int in = 0; in < 4; ++in) {
                const int row0 = bm + wm + quad * 4;
                const int col  = bn + in * 16 + lr;
#pragma unroll
                for (int r = 0; r < 4; ++r)
                    out[(size_t)(row0 + r) * 2048 + col] = acc[in][r];
            }
        }
    }
}

// ---------------------------------------------------------------------------
extern "C" void kernel_launch(void* const* d_in, const int* in_sizes, int n_in,
                              void* d_out, int out_size, void* d_ws, size_t ws_size,
                              hipStream_t stream) {
    const float* x        = (const float*)d_in[0];  // [2048, 2048]
    const float* Wq       = (const float*)d_in[1];  // [2048, 2048]
    const float* Wk       = (const float*)d_in[2];  // [512, 2048]
    const float* Wv       = (const float*)d_in[3];  // [512, 2048]
    const float* Wo       = (const float*)d_in[4];  // [2048, 2048]
    const float* inv_freq = (const float*)d_in[5];  // [32]
    float* out = (float*)d_out;                     // [2048, 2048] fp32

    const size_t ME = 1 << 20;
    u16* xb   = (u16*)d_ws;          // 4M  x bf16
    u16* wqkv = xb   + 4 * ME;       // 6M  [3072][2048]
    u16* wob  = wqkv + 6 * ME;       // 4M
    u16* qhb  = wob  + 4 * ME;       // 4M  Q[h][s][d]  (pre-scaled, exp2 domain)
    u16* khb  = qhb  + 4 * ME;       // 1M  K[kv][s][d]
    u16* vtb  = khb  + 1 * ME;       // 1M  Vt[kv][d][s]
    u16* aob  = vtb  + 1 * ME;       // 4M  ao[s][h*64+d]
    float2* cstab = (float2*)(aob + 4 * ME);  // 512KB  [2048][32] {cos,sin}

    // barrier + work-queue counters: carved from the end of the workspace
    // (well past the 48.5MB used above; zeroed every launch via async memset,
    // which is graph-capture-safe).
    u32* ctr = (u32*)((char*)d_ws + ((ws_size - 256) & ~(size_t)63));
    hipMemsetAsync(ctr, 0, 8, stream);

    fused_all<<<NBLK, 256, 0, stream>>>(
        x, Wq, Wk, Wv, Wo, inv_freq,
        xb, wqkv, wob, qhb, khb, vtb, aob, cstab,
        out, ctr, ctr + 1);
}

// Round 9
// 208.300 us; speedup vs baseline: 2.7017x; 2.7017x over previous
//
#include <hip/hip_runtime.h>
#include <hip/hip_bf16.h>
#include <math.h>

// B=1, S=2048, D=2048, H=32, KV=8, HD=64, G=4.
#define S_LEN 2048
#define D_MODEL 2048
#define N_H 32
#define N_KV 8
#define HD 64

typedef __attribute__((ext_vector_type(8))) short short8;   // 8 bf16 (A/B frag)
typedef __attribute__((ext_vector_type(4))) float floatx4;  // C/D frag
typedef unsigned short u16;
typedef unsigned int u32;

#define QSCALE 0.18033688011112042f   // (1/8) * log2(e): folded into Q -> exp2 domain

#if defined(__has_builtin)
#if __has_builtin(__builtin_amdgcn_exp2f)
#define EXP2(x) __builtin_amdgcn_exp2f(x)
#else
#define EXP2(x) __expf(0.6931471805599453f * (x))
#endif
#else
#define EXP2(x) __expf(0.6931471805599453f * (x))
#endif

// round-to-nearest-even fp32 -> bf16
__device__ __forceinline__ u16 f2bf(float f) {
    union { float f; u32 u; } v; v.f = f;
    u32 r = v.u + 0x7fffu + ((v.u >> 16) & 1u);
    return (u16)(r >> 16);
}

// async global->LDS, 16B/lane. LDS dest = wave-uniform base + lane*16.
__device__ __forceinline__ void gload16(const void* gp, void* lp) {
    __builtin_amdgcn_global_load_lds(
        (const __attribute__((address_space(1))) unsigned int*)gp,
        (__attribute__((address_space(3))) unsigned int*)lp,
        16, 0, 0);
}

// ---------------------------------------------------------------------------
// ROUND-15: verbatim revert to the round-13 (r7) 4-kernel file. The r14
// persistent-kernel fusion regressed 2.7x: phases stretched uniformly 2.4x
// (MfmaUtil 5% x 493us = same MFMA work as split kernels) because phase N+1
// read phase N's output while dirty in remote per-XCD L2s (G16 non-coherent
// -> slow probe path; FETCH 142MB at 5.4% HBM = latency-bound fetches),
// plus one-size 768-block grid for phases whose optima are 1024-2048.
// Lesson banked: kernel-boundary L2 flush is the FAST producer->consumer
// path on MI355X; don't fuse BW-shaped phases with device barriers.
// ---------------------------------------------------------------------------

// ---------------------------------------------------------------------------
// One-pass cast of all fp32 inputs to bf16 + RoPE sincos table fill.
// Grid-stride 2048 blocks, 7 unrolled independent float4 chunks/thread,
// plus cos/sin table: tab[s*32+d] = {cos,sin}(s*fr[d]) (same fp32 expression
// as the old epilogue -> bitwise-identical downstream).
// ---------------------------------------------------------------------------
__global__ __launch_bounds__(256) void cast_all(const float* __restrict__ x,
                                                const float* __restrict__ Wq,
                                                const float* __restrict__ Wk,
                                                const float* __restrict__ Wv,
                                                const float* __restrict__ Wo,
                                                const float* __restrict__ inv_freq,
                                                u16* __restrict__ xb,
                                                u16* __restrict__ wqkv,
                                                u16* __restrict__ wob,
                                                float2* __restrict__ tab) {
    const int t0 = blockIdx.x * 256 + threadIdx.x;        // 0..524287
#pragma unroll
    for (int j = 0; j < 7; ++j) {
        const int c = t0 + j * 524288;                    // float4 chunk id
        const int i = c * 4;                              // element index
        const int row = i >> 11;
        const int col = i & 2047;
        const float* src;
        u16* dst;
        if (row < 2048)      { src = x  + (size_t)row * 2048 + col;          dst = xb + i; }
        else if (row < 4096) { src = Wq + (size_t)(row - 2048) * 2048 + col; dst = wqkv + (i - 2048 * 2048); }
        else if (row < 4608) { src = Wk + (size_t)(row - 4096) * 2048 + col; dst = wqkv + (i - 2048 * 2048); }
        else if (row < 5120) { src = Wv + (size_t)(row - 4608) * 2048 + col; dst = wqkv + (i - 2048 * 2048); }
        else                 { src = Wo + (size_t)(row - 5120) * 2048 + col; dst = wob + (i - 5120 * 2048); }
        const float4 v = *(const float4*)src;
        ushort4 o;
        o.x = f2bf(v.x); o.y = f2bf(v.y); o.z = f2bf(v.z); o.w = f2bf(v.w);
        *(ushort4*)dst = o;
    }
    if (t0 < 65536) {                                     // s = t0>>5, d = t0&31
        const int s = t0 >> 5, d = t0 & 31;
        float sn, cs;
        sincosf((float)s * inv_freq[d], &sn, &cs);
        tab[t0] = make_float2(cs, sn);
    }
}

// ---------------------------------------------------------------------------
// QKV GEMM: C[M,N] = A[M,K] @ B[N,K]^T with fused RoPE/pack/scale epilogue.
// Proven r1 structure (64x128 tile, 4 waves of 32x64, BK=32, 24 KB LDS dbuf,
// grid (32,24)=768=3/CU, 12 waves/CU) + epilogue trig from the precomputed
// table (measured 47.0us, VALUBusy 19->15.9%).
// ---------------------------------------------------------------------------
__global__ __launch_bounds__(256) void gemm_qkv(const u16* __restrict__ A,
                                                const u16* __restrict__ B,
                                                u16* __restrict__ Qh,
                                                u16* __restrict__ Kh,
                                                u16* __restrict__ Vt,
                                                const float2* __restrict__ tab,
                                                int K) {
    __shared__ u16 As[2][64 * 32];
    __shared__ u16 Bs[2][128 * 32];
    const int tid  = threadIdx.x;
    const int w    = tid >> 6;
    const int lane = tid & 63;
    const int lr   = lane & 15;
    const int quad = lane >> 4;
    const int bm = blockIdx.x * 64, bn = blockIdx.y * 128;
    const int wm = (w & 1) * 32, wn = (w >> 1) * 64;

    // staging: thread t -> row t>>2 (0..63), chunk (t&3)*8
    const int srow = tid >> 2;
    const int sch  = (tid & 3) * 8;
    const u16* Ag = A + (size_t)(bm + srow) * K + sch;
    const u16* Bg = B + (size_t)(bn + srow) * K + sch;
    const int loff = srow * 32 + sch;          // byte off = tid*16
    const size_t gstride = (size_t)64 * K;

    floatx4 acc[2][4];
#pragma unroll
    for (int i = 0; i < 2; ++i)
#pragma unroll
        for (int j = 0; j < 4; ++j) acc[i][j] = floatx4{0.f, 0.f, 0.f, 0.f};

    gload16(Ag, &As[0][loff]);
    gload16(Bg, &Bs[0][loff]);
    gload16(Bg + gstride, &Bs[0][loff + 64 * 32]);
    __syncthreads();

    for (int k0 = 0; k0 < K; k0 += 32) {
        const int cur = (k0 >> 5) & 1;
        if (k0 + 32 < K) {                     // prefetch next k-tile
            gload16(Ag + k0 + 32, &As[cur ^ 1][loff]);
            gload16(Bg + k0 + 32, &Bs[cur ^ 1][loff]);
            gload16(Bg + gstride + k0 + 32, &Bs[cur ^ 1][loff + 64 * 32]);
        }
        short8 af[2], bf[4];
#pragma unroll
        for (int t = 0; t < 2; ++t)
            af[t] = *(const short8*)&As[cur][(wm + t * 16 + lr) * 32 + quad * 8];
#pragma unroll
        for (int t = 0; t < 4; ++t)
            bf[t] = *(const short8*)&Bs[cur][(wn + t * 16 + lr) * 32 + quad * 8];
#pragma unroll
        for (int im = 0; im < 2; ++im)
#pragma unroll
            for (int in = 0; in < 4; ++in)
                acc[im][in] = __builtin_amdgcn_mfma_f32_16x16x32_bf16(
                    af[im], bf[in], acc[im][in], 0, 0, 0);
        __syncthreads();   // publishes prefetched tile; guards buffer reuse
    }

    // C/D layout: col = lane&15 (+in*16), row = quad*4 + reg.
    // Wave covers cols c0..c0+63 = exactly one head (regions are 128-aligned).
    const int c0 = bn + wn;
    if (bn < 2048) {                           // ---- Q: rope + scale ----
        const int h = c0 >> 6;
#pragma unroll
        for (int p = 0; p < 2; ++p) {
            const int d = p * 16 + lr;         // 0..31
#pragma unroll
            for (int im = 0; im < 2; ++im)
#pragma unroll
                for (int r = 0; r < 4; ++r) {
                    const int s = bm + wm + im * 16 + quad * 4 + r;
                    const float2 t = tab[s * 32 + d];
                    const float cs = t.x, sn = t.y;
                    const float xl = acc[im][p][r], xh = acc[im][p + 2][r];
                    u16* qrow = Qh + ((size_t)h * S_LEN + s) * HD;
                    qrow[d]      = f2bf((xl * cs - xh * sn) * QSCALE);
                    qrow[d + 32] = f2bf((xh * cs + xl * sn) * QSCALE);
                }
        }
    } else if (bn < 2560) {                    // ---- K: rope ----
        const int kv = (c0 - 2048) >> 6;
#pragma unroll
        for (int p = 0; p < 2; ++p) {
            const int d = p * 16 + lr;
#pragma unroll
            for (int im = 0; im < 2; ++im)
#pragma unroll
                for (int r = 0; r < 4; ++r) {
                    const int s = bm + wm + im * 16 + quad * 4 + r;
                    const float2 t = tab[s * 32 + d];
                    const float cs = t.x, sn = t.y;
                    const float xl = acc[im][p][r], xh = acc[im][p + 2][r];
                    u16* krow = Kh + ((size_t)kv * S_LEN + s) * HD;
                    krow[d]      = f2bf(xl * cs - xh * sn);
                    krow[d + 32] = f2bf(xh * cs + xl * sn);
                }
        }
    } else {                                   // ---- V: transpose pack ----
        const int kv = (c0 - 2560) >> 6;
#pragma unroll
        for (int im = 0; im < 2; ++im)
#pragma unroll
            for (int in = 0; in < 4; ++in) {
                const int dfull = in * 16 + lr;
                const int s0 = bm + wm + im * 16 + quad * 4;
                ushort4 o;
                o.x = f2bf(acc[im][in][0]); o.y = f2bf(acc[im][in][1]);
                o.z = f2bf(acc[im][in][2]); o.w = f2bf(acc[im][in][3]);
                *(ushort4*)&Vt[((size_t)kv * HD + dfull) * S_LEN + s0] = o;
            }
    }
}

// ---------------------------------------------------------------------------
// Output projection GEMM. Round-8 config (kept): BK=64, XOR-chunk swizzle on
// source + reads, 32 KB LDS dbuf, grid (32,32) = 1024 = 4/CU.
// ---------------------------------------------------------------------------
__global__ __launch_bounds__(256) void gemm_out(const u16* __restrict__ A,
                                                const u16* __restrict__ B,
                                                float* __restrict__ Cf,
                                                int N, int K) {
    __shared__ u16 As[2][64 * 64];
    __shared__ u16 Bs[2][64 * 64];
    const int tid  = threadIdx.x;
    const int w    = tid >> 6;
    const int lane = tid & 63;
    const int lr   = lane & 15;
    const int quad = lane >> 4;
    const int bm = blockIdx.x * 64, bn = blockIdx.y * 64;
    const int wm = w * 16;

    const int srow = tid >> 3;          // 0..31
    const int sch  = tid & 7;           // 0..7

    floatx4 acc[4];
#pragma unroll
    for (int j = 0; j < 4; ++j) acc[j] = floatx4{0.f, 0.f, 0.f, 0.f};

#pragma unroll
    for (int j = 0; j < 2; ++j) {
        const int r = j * 32 + srow;
        gload16(A + (size_t)(bm + r) * K + ((sch ^ (r & 7)) * 8),
                &As[0][r * 64 + sch * 8]);
        gload16(B + (size_t)(bn + r) * K + ((sch ^ (r & 7)) * 8),
                &Bs[0][r * 64 + sch * 8]);
    }
    __syncthreads();

    for (int k0 = 0; k0 < K; k0 += 64) {
        const int cur = (k0 >> 6) & 1;
        if (k0 + 64 < K) {
            const int nb = cur ^ 1;
#pragma unroll
            for (int j = 0; j < 2; ++j) {
                const int r = j * 32 + srow;
                gload16(A + (size_t)(bm + r) * K + k0 + 64 + ((sch ^ (r & 7)) * 8),
                        &As[nb][r * 64 + sch * 8]);
                gload16(B + (size_t)(bn + r) * K + k0 + 64 + ((sch ^ (r & 7)) * 8),
                        &Bs[nb][r * 64 + sch * 8]);
            }
        }
#pragma unroll
        for (int kk = 0; kk < 2; ++kk) {
            short8 af, bf[4];
            {
                const int row = wm + lr;
                const int c   = kk * 4 + quad;
                af = *(const short8*)&As[cur][row * 64 + ((c ^ (row & 7)) * 8)];
            }
#pragma unroll
            for (int in = 0; in < 4; ++in) {
                const int row = in * 16 + lr;
                const int c   = kk * 4 + quad;
                bf[in] = *(const short8*)&Bs[cur][row * 64 + ((c ^ (row & 7)) * 8)];
            }
#pragma unroll
            for (int in = 0; in < 4; ++in)
                acc[in] = __builtin_amdgcn_mfma_f32_16x16x32_bf16(
                    af, bf[in], acc[in], 0, 0, 0);
        }
        __syncthreads();
    }

#pragma unroll
    for (int in = 0; in < 4; ++in) {
        const int row0 = bm + wm + quad * 4;
        const int col  = bn + in * 16 + lr;
#pragma unroll
        for (int r = 0; r < 4; ++r)
            Cf[(size_t)(row0 + r) * N + col] = acc[in][r];
    }
}

// ---------------------------------------------------------------------------
// MFMA flash attention (causal, GQA), exp2 domain, max-free softmax,
// swapped QK^T (kept: lane holds k-slots of one q-row; packed b32 P-writes
// via v_cvt_pk_bf16_f32; PV side and LDS P layout unchanged).
// ---------------------------------------------------------------------------
__global__ __launch_bounds__(256) void attn_mfma(const u16* __restrict__ Qh,
                                                 const u16* __restrict__ Kh,
                                                 const u16* __restrict__ Vt,
                                                 u16* __restrict__ AO) {
    __shared__ u16 QPs[64 * 64];         // Q tile, then P (wave-private rows)
    __shared__ u16 Ks[2][64 * 64];
    __shared__ u16 Vs[2][64 * 64];       // V^T tile: [d][s_local]

    const int bid = blockIdx.x;
    const int h   = bid & 31;
    const int qb  = 31 - (bid >> 5);     // heavy q-tiles first (qb 0..31)
    const int kv  = h >> 2;
    const int tid  = threadIdx.x;
    const int w    = tid >> 6;
    const int lr   = tid & 15;
    const int quad = (tid >> 4) & 3;
    const int grow = tid >> 3;           // staging row 0..31
    const int gp   = tid & 7;            // staging chunk position 0..7

    const u16* Qg = Qh + ((size_t)h * S_LEN + (size_t)qb * 64) * HD;
    const u16* Kg = Kh + (size_t)kv * S_LEN * HD;
    const u16* Vg = Vt + (size_t)kv * HD * S_LEN;

    // ---- stage Q + K/V tile 0 (swizzled global chunk per lane) ----
#pragma unroll
    for (int j = 0; j < 2; ++j) {
        const int r = j * 32 + grow;
        gload16(Qg + (size_t)r * HD + ((gp ^ (r & 7)) * 8), QPs + r * 64 + gp * 8);
        gload16(Kg + (size_t)r * HD + ((gp ^ (r & 7)) * 8), &Ks[0][r * 64 + gp * 8]);
        gload16(Vg + (size_t)r * S_LEN + ((gp ^ (r & 7)) * 8), &Vs[0][r * 64 + gp * 8]);
    }
    __syncthreads();

    const int wq0 = qb * 64 + w * 16;    // wave's first global q row

    // Q A-frags (wave-private rows w*16..w*16+15; swizzled read)
    short8 qf[2];
#pragma unroll
    for (int kh = 0; kh < 2; ++kh) {
        const int row = w * 16 + lr;
        const int c   = kh * 4 + quad;
        qf[kh] = *(const short8*)&QPs[row * 64 + ((c ^ (row & 7)) * 8)];
    }
    // no barrier needed: P writes below touch only this wave's own 16 rows

    // P-write lane constants (swizzled b32 writes, layout identical to old)
    const int q1  = quad >> 1;                       // source-chunk high bit
    const int lr7 = lr & 7;
    const int pwbase = (w * 16 + lr) * 64 + (quad & 1) * 4;  // elem base

    float l_lane = 0.f;
    floatx4 oacc[4];
#pragma unroll
    for (int dn = 0; dn < 4; ++dn) oacc[dn] = floatx4{0.f, 0.f, 0.f, 0.f};

    for (int kt = 0; kt <= qb; ++kt) {
        const int buf = kt & 1;
        if (kt < qb) {                   // prefetch next K/V tile
            const int nb = buf ^ 1;
#pragma unroll
            for (int j = 0; j < 2; ++j) {
                const int r = j * 32 + grow;
                gload16(Kg + (size_t)((kt + 1) * 64 + r) * HD + ((gp ^ (r & 7)) * 8),
                        &Ks[nb][r * 64 + gp * 8]);
                gload16(Vg + (size_t)r * S_LEN + (kt + 1) * 64 + ((gp ^ (r & 7)) * 8),
                        &Vs[nb][r * 64 + gp * 8]);
            }
        }
        if (64 * kt <= wq0 + 15) {       // wave has unmasked work this tile
            // ---- S^T = K Q^T (swapped: lane holds k-slots of q-row lr) ----
            floatx4 st[4];
#pragma unroll
            for (int in = 0; in < 4; ++in) st[in] = floatx4{0.f, 0.f, 0.f, 0.f};
#pragma unroll
            for (int in = 0; in < 4; ++in)
#pragma unroll
                for (int kh = 0; kh < 2; ++kh) {
                    const int row = in * 16 + lr;
                    const int c   = kh * 4 + quad;
                    const short8 kf = *(const short8*)
                        &Ks[buf][row * 64 + ((c ^ (row & 7)) * 8)];
                    st[in] = __builtin_amdgcn_mfma_f32_16x16x32_bf16(
                        kf, qf[kh], st[in], 0, 0, 0);
                }

            // ---- causal mask + max-free exp2 + l accumulation ----
            const bool need_mask = (kt * 64 + 63) > wq0;
            const int qglob = wq0 + lr;              // lane's global q row
#pragma unroll
            for (int in = 0; in < 4; ++in)
#pragma unroll
                for (int r = 0; r < 4; ++r) {
                    float s = st[in][r];
                    if (need_mask) {
                        const int kg = kt * 64 + in * 16 + quad * 4 + r;
                        if (kg > qglob) s = -1e30f;
                    }
                    const float p = EXP2(s);
                    st[in][r] = p;
                    l_lane += p;
                }

            // ---- P -> LDS: 8x b32 packed writes (layout = old swizzle) ----
#pragma unroll
            for (int in = 0; in < 4; ++in) {
                const int chunk = (((in * 2 + q1) ^ lr7) << 3);
                float2 lo2; lo2.x = st[in][0]; lo2.y = st[in][1];
                float2 hi2; hi2.x = st[in][2]; hi2.y = st[in][3];
                __hip_bfloat162 blo = __float22bfloat162_rn(lo2);
                __hip_bfloat162 bhi = __float22bfloat162_rn(hi2);
                *(u32*)&QPs[pwbase + chunk]     = *(u32*)&blo;
                *(u32*)&QPs[pwbase + chunk + 2] = *(u32*)&bhi;
            }

            // ---- O += P V (unchanged: LDS P layout identical) ----
#pragma unroll
            for (int kc = 0; kc < 2; ++kc) {
                const int prow = w * 16 + lr;
                const short8 pf = *(const short8*)
                    &QPs[prow * 64 + (((kc * 4 + quad) ^ (prow & 7)) * 8)];
#pragma unroll
                for (int dn = 0; dn < 4; ++dn) {
                    const int vrow = dn * 16 + lr;
                    const int c    = kc * 4 + quad;
                    const short8 vf = *(const short8*)
                        &Vs[buf][vrow * 64 + ((c ^ (vrow & 7)) * 8)];
                    oacc[dn] = __builtin_amdgcn_mfma_f32_16x16x32_bf16(
                        pf, vf, oacc[dn], 0, 0, 0);
                }
            }
        }
        __syncthreads();   // publishes prefetched tile; guards buffer reuse
    }

    // epilogue: l_lane holds partial l(q = w*16+lr); reduce over quad group
    float lv = l_lane;
    lv += __shfl_xor(lv, 16);
    lv += __shfl_xor(lv, 32);
    // O rows are q-local quad*4+r -> fetch that row's l via in-wave shfl
#pragma unroll
    for (int r = 0; r < 4; ++r) {
        const float inv = 1.f / __shfl(lv, quad * 4 + r);
        const size_t row = (size_t)(wq0 + quad * 4 + r);
#pragma unroll
        for (int dn = 0; dn < 4; ++dn)
            AO[row * D_MODEL + h * 64 + dn * 16 + lr] =
                f2bf(oacc[dn][r] * inv);
    }
}

// ---------------------------------------------------------------------------
extern "C" void kernel_launch(void* const* d_in, const int* in_sizes, int n_in,
                              void* d_out, int out_size, void* d_ws, size_t ws_size,
                              hipStream_t stream) {
    const float* x        = (const float*)d_in[0];  // [2048, 2048]
    const float* Wq       = (const float*)d_in[1];  // [2048, 2048]
    const float* Wk       = (const float*)d_in[2];  // [512, 2048]
    const float* Wv       = (const float*)d_in[3];  // [512, 2048]
    const float* Wo       = (const float*)d_in[4];  // [2048, 2048]
    const float* inv_freq = (const float*)d_in[5];  // [32]
    float* out = (float*)d_out;                     // [2048, 2048] fp32

    const size_t ME = 1 << 20;
    u16* xb   = (u16*)d_ws;          // 4M  x bf16
    u16* wqkv = xb   + 4 * ME;       // 6M  [3072][2048]
    u16* wob  = wqkv + 6 * ME;       // 4M
    u16* qhb  = wob  + 4 * ME;       // 4M  Q[h][s][d]  (pre-scaled, exp2 domain)
    u16* khb  = qhb  + 4 * ME;       // 1M  K[kv][s][d]
    u16* vtb  = khb  + 1 * ME;       // 1M  Vt[kv][d][s]
    u16* aob  = vtb  + 1 * ME;       // 4M  ao[s][h*64+d]
    float2* cstab = (float2*)(aob + 4 * ME);  // 512KB  [2048][32] {cos,sin}

    const dim3 b256(256);

    // single-pass bf16 casts (x + all weights) + RoPE table fill
    cast_all<<<2048, b256, 0, stream>>>(x, Wq, Wk, Wv, Wo, inv_freq,
                                        xb, wqkv, wob, cstab);

    // fused QKV projection + RoPE + pack (+ Q softmax/log2e scale)
    gemm_qkv<<<dim3(32, 24), b256, 0, stream>>>(
        xb, wqkv, qhb, khb, vtb, cstab, D_MODEL);

    // causal GQA flash attention (1024 blocks, 64 q-rows each)
    attn_mfma<<<dim3(1024), b256, 0, stream>>>(qhb, khb, vtb, aob);

    // output projection (64x64 tiles, BK=64 -> 1024 blocks = 4/CU)
    gemm_out<<<dim3(32, 32), b256, 0, stream>>>(
        aob, wob, out, D_MODEL, D_MODEL);
}